// Round 5
// baseline (324.906 us; speedup 1.0000x reference)
//
#include <hip/hip_runtime.h>
#include <hip/hip_bf16.h>

// ---------------- constants ----------------
#define EPS 1e-6f
#define NBH 32      // B*H
#define LSEQ 1024
#define DHD 64

typedef unsigned short u16;
typedef __bf16 bf16x8 __attribute__((ext_vector_type(8)));
typedef float f32x4 __attribute__((ext_vector_type(4)));

__device__ inline u16 f2bf(float f){
  union { float f; unsigned u; } un; un.f = f;
  unsigned u = un.u;
  u += 0x7fffu + ((u >> 16) & 1u);
  return (u16)(u >> 16);
}

__device__ inline float wred64(float v){
#pragma unroll
  for (int off = 32; off > 0; off >>= 1) v += __shfl_xor(v, off, 64);
  return v;
}

__device__ inline float wscan64(float v, int lane){
  float run = v;
#pragma unroll
  for (int off = 1; off < 64; off <<= 1){
    float t = __shfl_up(run, off, 64);
    if (lane >= off) run += t;
  }
  return run;   // inclusive
}

__device__ inline void gload_lds16(const u16* g, u16* l){
  __builtin_amdgcn_global_load_lds(
      (const __attribute__((address_space(1))) unsigned int*)g,
      (__attribute__((address_space(3))) unsigned int*)l, 16, 0, 0);
}

// ---------------- converts ----------------
__global__ __launch_bounds__(256) void f2bf_kernel(const float* __restrict__ in,
                                                   u16* __restrict__ out, int n4){
  int i = blockIdx.x * 256 + threadIdx.x;
  if (i < n4){
    float4 v = reinterpret_cast<const float4*>(in)[i];
    ushort4 o; o.x = f2bf(v.x); o.y = f2bf(v.y); o.z = f2bf(v.z); o.w = f2bf(v.w);
    reinterpret_cast<ushort4*>(out)[i] = o;
  }
}

// out[c][r] = bf16(in[r][c]);  R,C multiples of 32
__global__ __launch_bounds__(256) void transpose_f2bf(const float* __restrict__ in,
                                                      u16* __restrict__ out, int R, int C){
  __shared__ float tile[32][33];
  int x = threadIdx.x & 31, y = threadIdx.x >> 5;
  int r0 = blockIdx.y * 32, c0 = blockIdx.x * 32;
#pragma unroll
  for (int j = 0; j < 4; j++)
    tile[y + j*8][x] = in[(size_t)(r0 + y + j*8) * C + c0 + x];
  __syncthreads();
#pragma unroll
  for (int j = 0; j < 4; j++)
    out[(size_t)(c0 + y + j*8) * R + r0 + x] = f2bf(tile[x][y + j*8]);
}

// ---------------- bf16 MFMA GEMM (dbuf + XCD supertile swizzle) ----------------
// C[M,N] = act(A[M,K] @ Bt[N,K]^T + bias)
// ACT: 0 none, 2 gelu(exact)  (OM==1 applies sigmoid for col<2048 internally)
// OM: 0 f32 [M][N]; 1 fused-QKV remap to 3x[B,H,L,DH]; 2 f32 + resid; 3 bf16 [M][N]
// Grid is 1D = GX*GY blocks. Each XCD (wg&7) owns one SMxSN supertile of output
// tiles so its private L2 holds the supertile's A/B panels (panel reuse on-XCD).
// NSX = GX/SM supertiles along m.
template<int BM, int BN, int SM, int SN, int NSX, int ACT, int OM>
__global__ __launch_bounds__(256) void gemm_mfma(
    const u16* __restrict__ A, const u16* __restrict__ Bt,
    const float* __restrict__ bias, const float* __restrict__ resid,
    float* __restrict__ outF, u16* __restrict__ outB,
    int M, int N, int K)
{
  constexpr int BK = 64;
  constexpr int MI = BM / 32;
  constexpr int NJ = BN / 32;
  constexpr int RA = BM / 32;           // A staging rounds (256 thr x 16B)
  constexpr int RB = BN / 32;
  constexpr int NS = RA + RB;           // gload_lds per wave per stage
  __shared__ u16 As[2][BM * BK];
  __shared__ u16 Bs[2][BN * BK];
  const int tid = threadIdx.x;
  const int lane = tid & 63, wave = tid >> 6;
  const int lrow = lane & 15, lg = lane >> 4;

  // ---- XCD supertile swizzle ----
  int wg = blockIdx.x;
  int xcd = wg & 7, p = wg >> 3;
  int stx = xcd % NSX, sty = xcd / NSX;
  int lm = p % SM, ln = p / SM;
  const int m0 = (stx * SM + lm) * BM;
  const int n0 = (sty * SN + ln) * BN;

  const int wm = (wave >> 1) * (BM / 2), wn = (wave & 1) * (BN / 2);

  f32x4 acc[MI][NJ];
#pragma unroll
  for (int i = 0; i < MI; i++)
#pragma unroll
    for (int j = 0; j < NJ; j++) acc[i][j] = (f32x4){0.f, 0.f, 0.f, 0.f};

  const u16* Ab = A + (size_t)m0 * K;
  const u16* Bb = Bt + (size_t)n0 * K;

  auto STAGE = [&](int buf, int k0){
#pragma unroll
    for (int r = 0; r < RA; ++r){
      int c = r * 256 + tid;
      int row = c >> 3, kk = (c & 7) << 3;
      gload_lds16(Ab + (size_t)row * K + k0 + kk, &As[buf][(r * 256 + wave * 64) * 8]);
    }
#pragma unroll
    for (int r = 0; r < RB; ++r){
      int c = r * 256 + tid;
      int row = c >> 3, kk = (c & 7) << 3;
      gload_lds16(Bb + (size_t)row * K + k0 + kk, &Bs[buf][(r * 256 + wave * 64) * 8]);
    }
  };

  STAGE(0, 0);
  int cur = 0;
  for (int k0 = 0; k0 < K; k0 += BK){
    if (k0 + BK < K){
      STAGE(cur ^ 1, k0 + BK);          // prefetch next tile into other buffer
      if constexpr (NS == 8)      asm volatile("s_waitcnt vmcnt(8)" ::: "memory");
      else if constexpr (NS == 6) asm volatile("s_waitcnt vmcnt(6)" ::: "memory");
      else                        asm volatile("s_waitcnt vmcnt(0)" ::: "memory");
    } else {
      asm volatile("s_waitcnt vmcnt(0)" ::: "memory");
    }
    __builtin_amdgcn_s_barrier();       // all waves' current-tile LDS writes visible
    __builtin_amdgcn_sched_barrier(0);  // keep ds_reads below the barrier
#pragma unroll
    for (int kh = 0; kh < 2; ++kh){
      bf16x8 af[MI], bfv[NJ];
#pragma unroll
      for (int i = 0; i < MI; ++i)
        af[i] = *reinterpret_cast<const bf16x8*>(&As[cur][(wm + i * 16 + lrow) * BK + kh * 32 + lg * 8]);
#pragma unroll
      for (int j = 0; j < NJ; ++j)
        bfv[j] = *reinterpret_cast<const bf16x8*>(&Bs[cur][(wn + j * 16 + lrow) * BK + kh * 32 + lg * 8]);
#pragma unroll
      for (int i = 0; i < MI; ++i)
#pragma unroll
        for (int j = 0; j < NJ; ++j)
          acc[i][j] = __builtin_amdgcn_mfma_f32_16x16x32_bf16(af[i], bfv[j], acc[i][j], 0, 0, 0);
    }
    __builtin_amdgcn_s_barrier();       // all waves done reading buf[cur] before restage
    cur ^= 1;
  }

#pragma unroll
  for (int i = 0; i < MI; ++i){
#pragma unroll
    for (int j = 0; j < NJ; ++j){
      int col = n0 + wn + j * 16 + lrow;
      float bv = bias ? bias[col] : 0.f;
#pragma unroll
      for (int r = 0; r < 4; ++r){
        int row = m0 + wm + i * 16 + lg * 4 + r;
        float x = acc[i][j][r] + bv;
        if (OM == 1){
          if (col < 2048) x = 1.f / (1.f + expf(-x));
          int which = col >> 10, cc = col & 1023, h = cc >> 6, d = cc & 63;
          int b = row >> 10, l = row & 1023;
          outF[(size_t)which * (2048ull * 1024) +
               (((size_t)(b * 16 + h)) * 1024 + l) * 64 + d] = x;
        } else {
          if (ACT == 2) x = 0.5f * x * (1.f + erff(x * 0.70710678118654752f));
          if (OM == 0) outF[(size_t)row * N + col] = x;
          else if (OM == 2){
            size_t idx = (size_t)row * N + col;
            outF[idx] = x + resid[idx];
          } else {
            outB[(size_t)row * N + col] = f2bf(x);
          }
        }
      }
    }
  }
}

// ---------------- attention scalar pipeline (chunked Gram-tile form) ----------------
__global__ __launch_bounds__(256) void chunk_sums(const float* __restrict__ k, const float* __restrict__ q,
                                                  float* __restrict__ ck, float* __restrict__ cq){
  int blk = blockIdx.x;
  int lane = threadIdx.x & 63, wave = threadIdx.x >> 6;
  size_t base = (size_t)blk * 64 * DHD;
  float sk = 0.f, sq = 0.f;
  for (int l = wave * 16; l < wave * 16 + 16; l++){
    sk += k[base + l * 64 + lane];
    sq += q[base + l * 64 + lane];
  }
  __shared__ float rd[2][4][64];
  rd[0][wave][lane] = sk; rd[1][wave][lane] = sq;
  __syncthreads();
  if (wave == 0){
    ck[(size_t)blk * 64 + lane] = rd[0][0][lane] + rd[0][1][lane] + rd[0][2][lane] + rd[0][3][lane];
    cq[(size_t)blk * 64 + lane] = rd[1][0][lane] + rd[1][1][lane] + rd[1][2][lane] + rd[1][3][lane];
  }
}

// sink_in/src_out via G = Q K^T tile; also emits weighted chunk sums cso=sum so*k, cqsi=sum si*q
__global__ __launch_bounds__(256) void sink_tile(
    const float* __restrict__ q, const float* __restrict__ k,
    const float* __restrict__ ck, const float* __restrict__ cq,
    float* __restrict__ sink_in, float* __restrict__ src_out,
    float* __restrict__ cso, float* __restrict__ cqsi)
{
  int blk = blockIdx.x, bh = blk >> 4, c = blk & 15;
  int tid = threadIdx.x, lane = tid & 63, wave = tid >> 6;
  __shared__ float qT[64][65], kT[64][65], G[64][66];
  __shared__ float PK[64], PQ[64];
  __shared__ float rk[64], rq[64], crk[64], crq[64], siv[64], sov[64];
  __shared__ float rd[2][4][64];
  size_t base = ((size_t)bh * LSEQ + c * 64) * DHD;
  const float* qb = q + base; const float* kb = k + base;
  for (int c4 = tid; c4 < 1024; c4 += 256){
    int l = c4 >> 4, d0 = (c4 & 15) * 4;
    float4 qv = *reinterpret_cast<const float4*>(qb + c4 * 4);
    qT[d0+0][l] = qv.x; qT[d0+1][l] = qv.y; qT[d0+2][l] = qv.z; qT[d0+3][l] = qv.w;
    float4 kv = *reinterpret_cast<const float4*>(kb + c4 * 4);
    kT[d0+0][l] = kv.x; kT[d0+1][l] = kv.y; kT[d0+2][l] = kv.z; kT[d0+3][l] = kv.w;
  }
  if (tid < 64){
    float pk = 0.f, pq = 0.f;
    for (int cc = 0; cc < c; cc++){
      pk += ck[((size_t)bh * 16 + cc) * 64 + tid];
      pq += cq[((size_t)bh * 16 + cc) * 64 + tid];
    }
    PK[tid] = pk; PQ[tid] = pq;
  }
  __syncthreads();
  for (int j = wave * 16; j < wave * 16 + 16; j++){
    float s = wred64(kT[lane][j]);  if (lane == 0) rk[j] = s;
    float s2 = wred64(qT[lane][j]); if (lane == 0) rq[j] = s2;
  }
  float sumPK = wred64(PK[lane]);
  float sumPQ = wred64(PQ[lane]);
  {
    int l = lane, g = wave;
    float qrow[64];
#pragma unroll
    for (int d = 0; d < 64; d++) qrow[d] = qT[d][l];
    float p[16] = {};
    for (int d = 0; d < 64; d++){
      float qv = qrow[d];
#pragma unroll
      for (int j4 = 0; j4 < 4; j4++){
        float4 kk = *reinterpret_cast<const float4*>(&kT[d][g * 16 + j4 * 4]);
        p[j4*4+0] += qv * kk.x; p[j4*4+1] += qv * kk.y;
        p[j4*4+2] += qv * kk.z; p[j4*4+3] += qv * kk.w;
      }
    }
#pragma unroll
    for (int jj = 0; jj < 16; jj++) G[l][g * 16 + jj] = p[jj];
  }
  __syncthreads();
  if (wave == 0)      crk[lane] = wscan64(rk[lane], lane);
  else if (wave == 1) crq[lane] = wscan64(rq[lane], lane);
  __syncthreads();
  const float EPS2 = 64.f * EPS * EPS;
  for (int l = wave * 16; l < wave * 16 + 16; l++){
    float t1 = ((lane <= l) ? G[l][lane] : 0.f) + qT[lane][l] * PK[lane];
    float s1 = wred64(t1);
    float t2 = ((lane <= l) ? G[lane][l] : 0.f) + kT[lane][l] * PQ[lane];
    float s2 = wred64(t2);
    if (lane == 0){
      int L = c * 64 + l; float nrm = (float)(L + 1);
      float den1 = s1 + EPS * rq[l] + EPS * (sumPK + crk[l]) + EPS2;
      float den2 = s2 + EPS * rk[l] + EPS * (sumPQ + crq[l]) + EPS2;
      float si_ = nrm / den1, so_ = nrm / den2;
      sink_in[(size_t)bh * LSEQ + L] = si_;
      src_out[(size_t)bh * LSEQ + L] = so_;
      siv[l] = si_; sov[l] = so_;
    }
  }
  __syncthreads();
  float s1 = 0.f, s2 = 0.f;
  for (int l = wave * 16; l < wave * 16 + 16; l++){
    s1 += sov[l] * kT[lane][l];
    s2 += siv[l] * qT[lane][l];
  }
  rd[0][wave][lane] = s1; rd[1][wave][lane] = s2;
  __syncthreads();
  if (wave == 0){
    cso [(size_t)blk * 64 + lane] = rd[0][0][lane] + rd[0][1][lane] + rd[0][2][lane] + rd[0][3][lane];
    cqsi[(size_t)blk * 64 + lane] = rd[1][0][lane] + rd[1][1][lane] + rd[1][2][lane] + rd[1][3][lane];
  }
}

// cons_sink -> sa = sigmoid; cons_src -> clip -> ebuf = exp
__global__ __launch_bounds__(256) void cons_tile(
    const float* __restrict__ q, const float* __restrict__ k,
    const float* __restrict__ cso, const float* __restrict__ cqsi,
    const float* __restrict__ sink_in, const float* __restrict__ src_out,
    float* __restrict__ sa, float* __restrict__ ebuf)
{
  int blk = blockIdx.x, bh = blk >> 4, c = blk & 15;
  int tid = threadIdx.x, lane = tid & 63, wave = tid >> 6;
  __shared__ float qT[64][65], kT[64][65], G[64][66];
  __shared__ float PKso[64], PQsi[64];
  __shared__ float rk[64], rq[64], cwrk[64], cwrq[64], siv[64], sov[64];
  size_t base = ((size_t)bh * LSEQ + c * 64) * DHD;
  const float* qb = q + base; const float* kb = k + base;
  for (int c4 = tid; c4 < 1024; c4 += 256){
    int l = c4 >> 4, d0 = (c4 & 15) * 4;
    float4 qv = *reinterpret_cast<const float4*>(qb + c4 * 4);
    qT[d0+0][l] = qv.x; qT[d0+1][l] = qv.y; qT[d0+2][l] = qv.z; qT[d0+3][l] = qv.w;
    float4 kv = *reinterpret_cast<const float4*>(kb + c4 * 4);
    kT[d0+0][l] = kv.x; kT[d0+1][l] = kv.y; kT[d0+2][l] = kv.z; kT[d0+3][l] = kv.w;
  }
  if (tid < 64){
    float pk = 0.f, pq = 0.f;
    for (int cc = 0; cc < c; cc++){
      pk += cso [((size_t)bh * 16 + cc) * 64 + tid];
      pq += cqsi[((size_t)bh * 16 + cc) * 64 + tid];
    }
    PKso[tid] = pk; PQsi[tid] = pq;
  } else if (tid < 128){
    int l = tid - 64;
    sov[l] = src_out[(size_t)bh * LSEQ + c * 64 + l];
    siv[l] = sink_in[(size_t)bh * LSEQ + c * 64 + l];
  }
  __syncthreads();
  for (int j = wave * 16; j < wave * 16 + 16; j++){
    float s = wred64(kT[lane][j]);  if (lane == 0) rk[j] = s;
    float s2 = wred64(qT[lane][j]); if (lane == 0) rq[j] = s2;
  }
  float sumPKso = wred64(PKso[lane]);
  float sumPQsi = wred64(PQsi[lane]);
  {
    int l = lane, g = wave;
    float qrow[64];
#pragma unroll
    for (int d = 0; d < 64; d++) qrow[d] = qT[d][l];
    float p[16] = {};
    for (int d = 0; d < 64; d++){
      float qv = qrow[d];
#pragma unroll
      for (int j4 = 0; j4 < 4; j4++){
        float4 kk = *reinterpret_cast<const float4*>(&kT[d][g * 16 + j4 * 4]);
        p[j4*4+0] += qv * kk.x; p[j4*4+1] += qv * kk.y;
        p[j4*4+2] += qv * kk.z; p[j4*4+3] += qv * kk.w;
      }
    }
#pragma unroll
    for (int jj = 0; jj < 16; jj++) G[l][g * 16 + jj] = p[jj];
  }
  __syncthreads();
  if (wave == 0)      cwrk[lane] = wscan64(sov[lane] * rk[lane], lane);
  else if (wave == 1) cwrq[lane] = wscan64(siv[lane] * rq[lane], lane);
  __syncthreads();
  const float EPS2 = 64.f * EPS * EPS;
  for (int l = wave * 16; l < wave * 16 + 16; l++){
    float t3 = ((lane <= l) ? sov[lane] * G[l][lane] : 0.f) + qT[lane][l] * PKso[lane];
    float s3 = wred64(t3);
    float t4 = ((lane <= l) ? siv[lane] * G[lane][l] : 0.f) + kT[lane][l] * PQsi[lane];
    float s4 = wred64(t4);
    if (lane == 0){
      int L = c * 64 + l; float nrm = (float)(L + 1);
      float cs = (s3 + EPS * rq[l] + EPS * (sumPKso + cwrk[l]) + EPS2) / nrm;
      sa[(size_t)bh * LSEQ + L] = 1.f / (1.f + expf(-cs));
      float c2 = (s4 + EPS * rk[l] + EPS * (sumPQsi + cwrq[l]) + EPS2) / nrm;
      c2 = fminf(1.f, fmaxf(-1.f, c2));
      ebuf[(size_t)bh * LSEQ + L] = expf(c2);
    }
  }
}

// src_comp = e / cumsum(e) * (l+1)
__global__ __launch_bounds__(64) void srccomp_kernel(const float* __restrict__ ebuf, float* __restrict__ sc){
  int bh = blockIdx.x; int lane = threadIdx.x;
  const float* eb = ebuf + (size_t)bh * LSEQ;
  float loc[16]; float s = 0.f;
#pragma unroll
  for (int i = 0; i < 16; i++){ loc[i] = eb[lane * 16 + i]; s += loc[i]; }
  float run = wscan64(s, lane);
  float acc = run - s;
  float* scb = sc + (size_t)bh * LSEQ;
#pragma unroll
  for (int i = 0; i < 16; i++){
    acc += loc[i];
    scb[lane * 16 + i] = loc[i] / acc * (float)(lane * 16 + i + 1);
  }
}

// qs = q*sink_in/(l+1);  vs = v*src_comp
__global__ __launch_bounds__(256) void scale_kernel(const float* __restrict__ q, const float* __restrict__ v,
                                                    const float* __restrict__ si, const float* __restrict__ sc,
                                                    float* __restrict__ qs, float* __restrict__ vs){
  int i0 = (blockIdx.x * 256 + threadIdx.x) * 8;
  int r = i0 >> 6; int l = r & (LSEQ - 1);
  float qcoef = si[r] / (float)(l + 1);
  float vcoef = sc[r];
#pragma unroll
  for (int t = 0; t < 8; t += 4){
    float4 qv = *reinterpret_cast<const float4*>(q + i0 + t);
    float4 vv = *reinterpret_cast<const float4*>(v + i0 + t);
    *reinterpret_cast<float4*>(qs + i0 + t) = make_float4(qv.x*qcoef, qv.y*qcoef, qv.z*qcoef, qv.w*qcoef);
    *reinterpret_cast<float4*>(vs + i0 + t) = make_float4(vv.x*vcoef, vv.y*vcoef, vv.z*vcoef, vv.w*vcoef);
  }
}

// ---------------- chunked causal linear attention ----------------
__global__ __launch_bounds__(256) void phaseA(const float* __restrict__ k, const float* __restrict__ vs,
                                              float* __restrict__ S){
  int blk = blockIdx.x; int bh = blk >> 4, c = blk & 15;
  __shared__ float ks[64][68], vss[64][68];
  int tid = threadIdx.x;
  size_t base = ((size_t)bh * LSEQ + c * 64) * DHD;
  const float* kb = k + base; const float* vb = vs + base;
  for (int c4 = tid; c4 < 1024; c4 += 256){
    int l = c4 >> 4, d0 = (c4 & 15) * 4;
    *reinterpret_cast<float4*>(&ks[l][d0])  = *reinterpret_cast<const float4*>(kb + c4 * 4);
    *reinterpret_cast<float4*>(&vss[l][d0]) = *reinterpret_cast<const float4*>(vb + c4 * 4);
  }
  __syncthreads();
  int m = tid >> 2, dg = tid & 3;
  float acc[16] = {};
  for (int l = 0; l < 64; l++){
    float vm = vss[l][m];
#pragma unroll
    for (int d4 = 0; d4 < 4; d4++){
      float4 kk = *reinterpret_cast<const float4*>(&ks[l][dg * 16 + d4 * 4]);
      acc[d4*4+0] += vm * kk.x; acc[d4*4+1] += vm * kk.y;
      acc[d4*4+2] += vm * kk.z; acc[d4*4+3] += vm * kk.w;
    }
  }
  float* Sb = S + (size_t)blk * 4096 + m * 64 + dg * 16;
#pragma unroll
  for (int d4 = 0; d4 < 4; d4++)
    *reinterpret_cast<float4*>(Sb + d4 * 4) =
        make_float4(acc[d4*4], acc[d4*4+1], acc[d4*4+2], acc[d4*4+3]);
}

__global__ __launch_bounds__(256) void phaseB(const float* __restrict__ S, float* __restrict__ KVp){
  int bh = blockIdx.x; int tid = threadIdx.x;
  int off = tid * 16;
  float acc[16] = {};
  for (int c = 0; c < 16; c++){
    size_t idx = ((size_t)bh * 16 + c) * 4096 + off;
#pragma unroll
    for (int t = 0; t < 4; t++)
      *reinterpret_cast<float4*>(KVp + idx + t * 4) =
          make_float4(acc[t*4], acc[t*4+1], acc[t*4+2], acc[t*4+3]);
#pragma unroll
    for (int t = 0; t < 4; t++){
      float4 sv = *reinterpret_cast<const float4*>(S + idx + t * 4);
      acc[t*4] += sv.x; acc[t*4+1] += sv.y; acc[t*4+2] += sv.z; acc[t*4+3] += sv.w;
    }
  }
}

__global__ __launch_bounds__(256) void phaseC(const float* __restrict__ qs, const float* __restrict__ k,
                                              const float* __restrict__ vs, const float* __restrict__ KVp,
                                              const float* __restrict__ sa, u16* __restrict__ x){
  int blk = blockIdx.x; int bh = blk >> 4, c = blk & 15;
  int b = bh >> 4, h = bh & 15;
  __shared__ float qsT[64][65];
  __shared__ float kT[64][68];
  __shared__ float vss[64][68];
  __shared__ float kvs[64][68];
  __shared__ float Ps[64][66];
  int tid = threadIdx.x;
  size_t base = ((size_t)bh * LSEQ + c * 64) * DHD;
  const float* qb = qs + base; const float* kb = k + base; const float* vb = vs + base;
  const float* kvb = KVp + (size_t)blk * 4096;
  for (int c4 = tid; c4 < 1024; c4 += 256){
    int l = c4 >> 4, d0 = (c4 & 15) * 4;
    float4 qv = *reinterpret_cast<const float4*>(qb + c4 * 4);
    qsT[d0+0][l] = qv.x; qsT[d0+1][l] = qv.y; qsT[d0+2][l] = qv.z; qsT[d0+3][l] = qv.w;
    float4 kv4 = *reinterpret_cast<const float4*>(kb + c4 * 4);
    kT[d0+0][l] = kv4.x; kT[d0+1][l] = kv4.y; kT[d0+2][l] = kv4.z; kT[d0+3][l] = kv4.w;
    *reinterpret_cast<float4*>(&vss[l][d0]) = *reinterpret_cast<const float4*>(vb + c4 * 4);
    *reinterpret_cast<float4*>(&kvs[l][d0]) = *reinterpret_cast<const float4*>(kvb + c4 * 4);
  }
  __syncthreads();
  int l = tid & 63, g = tid >> 6;
  float qrow[64];
#pragma unroll
  for (int d = 0; d < 64; d++) qrow[d] = qsT[d][l];

  float p[16] = {};
  for (int d = 0; d < 64; d++){
    float qv = qrow[d];
#pragma unroll
    for (int j4 = 0; j4 < 4; j4++){
      float4 kk = *reinterpret_cast<const float4*>(&kT[d][g * 16 + j4 * 4]);
      p[j4*4+0] += qv * kk.x; p[j4*4+1] += qv * kk.y;
      p[j4*4+2] += qv * kk.z; p[j4*4+3] += qv * kk.w;
    }
  }
#pragma unroll
  for (int jj = 0; jj < 16; jj++){
    int j = g * 16 + jj;
    Ps[l][j] = (j <= l) ? p[jj] : 0.f;
  }
  __syncthreads();

  float acc[16];
#pragma unroll
  for (int mm = 0; mm < 16; mm++){
    float a = 0.f;
#pragma unroll
    for (int d4 = 0; d4 < 16; d4++){
      float4 kv4 = *reinterpret_cast<const float4*>(&kvs[g * 16 + mm][d4 * 4]);
      a += qrow[d4*4+0]*kv4.x + qrow[d4*4+1]*kv4.y + qrow[d4*4+2]*kv4.z + qrow[d4*4+3]*kv4.w;
    }
    acc[mm] = a;
  }
  for (int j = 0; j < 64; j++){
    float pv = Ps[l][j];
#pragma unroll
    for (int m4 = 0; m4 < 4; m4++){
      float4 vv = *reinterpret_cast<const float4*>(&vss[j][g * 16 + m4 * 4]);
      acc[m4*4+0] += pv * vv.x; acc[m4*4+1] += pv * vv.y;
      acc[m4*4+2] += pv * vv.z; acc[m4*4+3] += pv * vv.w;
    }
  }
  float sav = sa[(size_t)bh * LSEQ + c * 64 + l];
  u16* xo = x + ((size_t)(b * 1024 + c * 64 + l)) * 1024 + h * 64 + g * 16;
#pragma unroll
  for (int mm = 0; mm < 16; mm++) xo[mm] = f2bf(acc[mm] * sav);
}

// ---------------- layernorm ----------------
__global__ __launch_bounds__(256) void ln_kernel(const float* __restrict__ xin, const float* __restrict__ g,
                                                 const float* __restrict__ b, float* __restrict__ out,
                                                 u16* __restrict__ outbf){
  int row = blockIdx.x; int tid = threadIdx.x;
  int lane = tid & 63, wave = tid >> 6;
  const float* xr = xin + (size_t)row * 1024;
  float4 v = *reinterpret_cast<const float4*>(xr + tid * 4);
  float s = v.x + v.y + v.z + v.w;
  float s2 = v.x*v.x + v.y*v.y + v.z*v.z + v.w*v.w;
  s = wred64(s); s2 = wred64(s2);
  __shared__ float red[2][4];
  if (lane == 0){ red[0][wave] = s; red[1][wave] = s2; }
  __syncthreads();
  float S = red[0][0] + red[0][1] + red[0][2] + red[0][3];
  float S2 = red[1][0] + red[1][1] + red[1][2] + red[1][3];
  float mean = S * (1.f / 1024.f);
  float var = S2 * (1.f / 1024.f) - mean * mean;
  float inv = rsqrtf(var + 1e-5f);
  float4 gv = *reinterpret_cast<const float4*>(g + tid * 4);
  float4 bv = *reinterpret_cast<const float4*>(b + tid * 4);
  float y0 = (v.x - mean) * inv * gv.x + bv.x;
  float y1 = (v.y - mean) * inv * gv.y + bv.y;
  float y2 = (v.z - mean) * inv * gv.z + bv.z;
  float y3 = (v.w - mean) * inv * gv.w + bv.w;
  *reinterpret_cast<float4*>(out + (size_t)row * 1024 + tid * 4) = make_float4(y0, y1, y2, y3);
  if (outbf){
    ushort4 o; o.x = f2bf(y0); o.y = f2bf(y1); o.z = f2bf(y2); o.w = f2bf(y3);
    *reinterpret_cast<ushort4*>(outbf + (size_t)row * 1024 + tid * 4) = o;
  }
}

// ---------------- launch ----------------
extern "C" void kernel_launch(void* const* d_in, const int* in_sizes, int n_in,
                              void* d_out, int out_size, void* d_ws, size_t ws_size,
                              hipStream_t stream){
  (void)in_sizes; (void)n_in; (void)out_size; (void)ws_size;
  const float* inputs = (const float*)d_in[0];
  const float* Wq = (const float*)d_in[2];  const float* bq = (const float*)d_in[3];
  const float* Wk = (const float*)d_in[4];  const float* bk = (const float*)d_in[5];
  const float* Wv = (const float*)d_in[6];  const float* bv = (const float*)d_in[7];
  const float* Wo = (const float*)d_in[8];  const float* bo = (const float*)d_in[9];
  const float* ln1g = (const float*)d_in[10]; const float* ln1b = (const float*)d_in[11];
  const float* W1 = (const float*)d_in[12]; const float* b1 = (const float*)d_in[13];
  const float* W2 = (const float*)d_in[14]; const float* b2 = (const float*)d_in[15];
  const float* ln2g = (const float*)d_in[16]; const float* ln2b = (const float*)d_in[17];
  float* out = (float*)d_out;

  char* wsp = (char*)d_ws; size_t off = 0;
  auto alloc = [&](size_t bytes) -> void* {
    off = (off + 255) & ~(size_t)255;
    void* p = wsp + off; off += bytes; return p;
  };
  const size_t MD = (size_t)2048 * 1024;
  u16* Xbf    = (u16*)alloc(MD * 2);
  u16* WqkvT  = (u16*)alloc((size_t)3 * 1024 * 1024 * 2);
  u16* WoT    = (u16*)alloc((size_t)1024 * 1024 * 2);
  u16* W1T    = (u16*)alloc((size_t)4096 * 1024 * 2);
  u16* W2T    = (u16*)alloc((size_t)4096 * 1024 * 2);
  float* bqkv = (float*)alloc(3072 * 4);
  float* qkvb = (float*)alloc(3 * MD * 4);
  float* qb = qkvb; float* kb = qkvb + MD; float* vb = qkvb + 2 * MD;
  float* c1 = (float*)alloc(MD * 4);            // qs
  float* c2 = (float*)alloc(MD * 4);            // vs
  float* ckb  = (float*)alloc((size_t)512 * 64 * 4);
  float* cqb  = (float*)alloc((size_t)512 * 64 * 4);
  float* csob = (float*)alloc((size_t)512 * 64 * 4);
  float* cqsib= (float*)alloc((size_t)512 * 64 * 4);
  float* sink_in = (float*)alloc(NBH * LSEQ * 4);
  float* src_out = (float*)alloc(NBH * LSEQ * 4);
  float* sabuf   = (float*)alloc(NBH * LSEQ * 4);
  float* ebuf    = (float*)alloc(NBH * LSEQ * 4);
  float* scbuf   = (float*)alloc(NBH * LSEQ * 4);
  float* Sbuf = (float*)alloc((size_t)NBH * 16 * 4096 * 4);
  float* KVp  = (float*)alloc((size_t)NBH * 16 * 4096 * 4);
  u16* xatt   = (u16*)alloc(MD * 2);
  u16* g1     = (u16*)alloc((size_t)2048 * 4096 * 2);
  float* s1 = qb;
  float* hbuf = vb;
  u16* hbf = (u16*)Sbuf;
  float* zbuf = kb;

  // converts + weight prep
  f2bf_kernel<<<2048, 256, 0, stream>>>(inputs, Xbf, (int)(MD / 4));
  transpose_f2bf<<<dim3(32, 32), 256, 0, stream>>>(Wq, WqkvT, 1024, 1024);
  transpose_f2bf<<<dim3(32, 32), 256, 0, stream>>>(Wk, WqkvT + 1024 * 1024, 1024, 1024);
  transpose_f2bf<<<dim3(32, 32), 256, 0, stream>>>(Wv, WqkvT + 2 * 1024 * 1024, 1024, 1024);
  transpose_f2bf<<<dim3(32, 32), 256, 0, stream>>>(Wo, WoT, 1024, 1024);
  transpose_f2bf<<<dim3(128, 32), 256, 0, stream>>>(W1, W1T, 1024, 4096);
  transpose_f2bf<<<dim3(32, 128), 256, 0, stream>>>(W2, W2T, 4096, 1024);
  hipMemcpyAsync(bqkv,        bq, 1024 * 4, hipMemcpyDeviceToDevice, stream);
  hipMemcpyAsync(bqkv + 1024, bk, 1024 * 4, hipMemcpyDeviceToDevice, stream);
  hipMemcpyAsync(bqkv + 2048, bv, 1024 * 4, hipMemcpyDeviceToDevice, stream);

  // fused QKV projection: grid 16x24 tiles -> supertile 8x6 per XCD (NSX = 16/8 = 2)
  gemm_mfma<128, 128, 8, 6, 2, 0, 1><<<384, 256, 0, stream>>>(
      Xbf, WqkvT, bqkv, nullptr, qkvb, nullptr, 2048, 3072, 1024);

  // attention scalars (chunked Gram-tile pipeline)
  chunk_sums<<<512, 256, 0, stream>>>(kb, qb, ckb, cqb);
  sink_tile<<<512, 256, 0, stream>>>(qb, kb, ckb, cqb, sink_in, src_out, csob, cqsib);
  cons_tile<<<512, 256, 0, stream>>>(qb, kb, csob, cqsib, sink_in, src_out, sabuf, ebuf);
  srccomp_kernel<<<32, 64, 0, stream>>>(ebuf, scbuf);
  scale_kernel<<<1024, 256, 0, stream>>>(qb, vb, sink_in, scbuf, c1, c2);

  // chunked causal linear attention
  phaseA<<<512, 256, 0, stream>>>(kb, c2, Sbuf);
  phaseB<<<32, 256, 0, stream>>>(Sbuf, KVp);
  phaseC<<<512, 256, 0, stream>>>(c1, kb, c2, KVp, sabuf, xatt);

  // output projection + residual: grid 16x16 (BN=64) -> supertile 8x4 (NSX=2)
  gemm_mfma<128, 64, 8, 4, 2, 0, 2><<<256, 256, 0, stream>>>(
      xatt, WoT, bo, inputs, s1, nullptr, 2048, 1024, 1024);
  ln_kernel<<<2048, 256, 0, stream>>>(s1, ln1g, ln1b, hbuf, hbf);

  // FFN1: grid 16x32 -> supertile 8x8 (NSX=2)
  gemm_mfma<128, 128, 8, 8, 2, 2, 3><<<512, 256, 0, stream>>>(
      hbf, W1T, b1, nullptr, nullptr, g1, 2048, 4096, 1024);
  // FFN2: grid 16x16 (BN=64) -> supertile 8x4 (NSX=2)
  gemm_mfma<128, 64, 8, 4, 2, 0, 2><<<256, 256, 0, stream>>>(
      g1, W2T, b2, hbuf, zbuf, nullptr, 2048, 1024, 4096);
  ln_kernel<<<2048, 256, 0, stream>>>(zbuf, ln2g, ln2b, out, nullptr);
}

// Round 6
// 282.983 us; speedup vs baseline: 1.1481x; 1.1481x over previous
//
#include <hip/hip_runtime.h>
#include <hip/hip_bf16.h>

// ---------------- constants ----------------
#define EPS 1e-6f
#define NBH 32      // B*H
#define LSEQ 1024
#define DHD 64

typedef unsigned short u16;
typedef __bf16 bf16x8 __attribute__((ext_vector_type(8)));
typedef float f32x4 __attribute__((ext_vector_type(4)));

__device__ inline u16 f2bf(float f){
  union { float f; unsigned u; } un; un.f = f;
  unsigned u = un.u;
  u += 0x7fffu + ((u >> 16) & 1u);
  return (u16)(u >> 16);
}

__device__ inline float wred64(float v){
#pragma unroll
  for (int off = 32; off > 0; off >>= 1) v += __shfl_xor(v, off, 64);
  return v;
}

__device__ inline float wscan64(float v, int lane){
  float run = v;
#pragma unroll
  for (int off = 1; off < 64; off <<= 1){
    float t = __shfl_up(run, off, 64);
    if (lane >= off) run += t;
  }
  return run;   // inclusive
}

__device__ inline void gload_lds16(const u16* g, u16* l){
  __builtin_amdgcn_global_load_lds(
      (const __attribute__((address_space(1))) unsigned int*)g,
      (__attribute__((address_space(3))) unsigned int*)l, 16, 0, 0);
}

// ---------------- converts ----------------
__global__ __launch_bounds__(256) void f2bf_kernel(const float* __restrict__ in,
                                                   u16* __restrict__ out, int n4){
  int i = blockIdx.x * 256 + threadIdx.x;
  if (i < n4){
    float4 v = reinterpret_cast<const float4*>(in)[i];
    ushort4 o; o.x = f2bf(v.x); o.y = f2bf(v.y); o.z = f2bf(v.z); o.w = f2bf(v.w);
    reinterpret_cast<ushort4*>(out)[i] = o;
  }
}

// generic 32x32-tile transpose+convert: out[c][r] = bf16(in[r][c])
__device__ inline void tr_tile(const float* in, u16* out, int R, int C){
  __shared__ float tile[32][33];
  int x = threadIdx.x & 31, y = threadIdx.x >> 5;
  int r0 = blockIdx.y * 32, c0 = blockIdx.x * 32;
#pragma unroll
  for (int j = 0; j < 4; j++)
    tile[y + j*8][x] = in[(size_t)(r0 + y + j*8) * C + c0 + x];
  __syncthreads();
#pragma unroll
  for (int j = 0; j < 4; j++)
    out[(size_t)(c0 + y + j*8) * R + r0 + x] = f2bf(tile[x][y + j*8]);
}

__global__ __launch_bounds__(256) void transpose_f2bf(const float* __restrict__ in,
                                                      u16* __restrict__ out, int R, int C){
  tr_tile(in, out, R, C);
}

// 4x 1024x1024 transposes in one launch (z selects matrix): Wq,Wk,Wv -> WqkvT; Wo -> WoT
__global__ __launch_bounds__(256) void transpose4_f2bf(
    const float* __restrict__ w0, const float* __restrict__ w1,
    const float* __restrict__ w2, const float* __restrict__ w3,
    u16* __restrict__ dqkv, u16* __restrict__ dwo){
  int z = blockIdx.z;
  const float* in = (z == 0) ? w0 : (z == 1) ? w1 : (z == 2) ? w2 : w3;
  u16* out = (z < 3) ? (dqkv + (size_t)z * 1024 * 1024) : dwo;
  tr_tile(in, out, 1024, 1024);
}

// gather q/k/v biases into one 3072 vector
__global__ __launch_bounds__(256) void bias_gather(const float* __restrict__ bq,
                                                   const float* __restrict__ bk,
                                                   const float* __restrict__ bv,
                                                   float* __restrict__ dst){
  int i = blockIdx.x * 256 + threadIdx.x;
  if (i < 3072){
    float v = (i < 1024) ? bq[i] : (i < 2048) ? bk[i - 1024] : bv[i - 2048];
    dst[i] = v;
  }
}

// ---------------- bf16 MFMA GEMM (single-buffer m97, small tiles, opt split-K) --------
// C[M,N] = act(A[M,K] @ Bt[N,K]^T + bias)
// ACT: 0 none, 2 gelu(exact)  (OM==1 applies sigmoid for col<2048 internally)
// OM: 0 f32 [M][N]; 1 fused-QKV remap to 3x[B,H,L,DH]; 2 f32 + resid;
//     3 bf16 [M][N]; 4 raw f32 partial (split-K slice z at outF + z*M*N, no bias)
// blockIdx: x = m-tile, y = n-tile, z = k-slice (gridDim.z slices)
template<int BM, int BN, int ACT, int OM>
__global__ __launch_bounds__(256) void gemm_mfma(
    const u16* __restrict__ A, const u16* __restrict__ Bt,
    const float* __restrict__ bias, const float* __restrict__ resid,
    float* __restrict__ outF, u16* __restrict__ outB,
    int M, int N, int K)
{
  constexpr int BK = 64;
  constexpr int MI = BM / 32;
  constexpr int NJ = BN / 32;
  constexpr int RA = BM / 32;           // A staging rounds (256 thr x 16B)
  constexpr int RB = BN / 32;
  __shared__ u16 As[BM * BK];
  __shared__ u16 Bs[BN * BK];
  const int tid = threadIdx.x;
  const int lane = tid & 63, wave = tid >> 6;
  const int lrow = lane & 15, lg = lane >> 4;
  const int m0 = blockIdx.x * BM, n0 = blockIdx.y * BN;
  const int wm = (wave >> 1) * (BM / 2), wn = (wave & 1) * (BN / 2);

  const int ksz = K / gridDim.z;
  const int k_begin = blockIdx.z * ksz;
  const int k_end = k_begin + ksz;

  f32x4 acc[MI][NJ];
#pragma unroll
  for (int i = 0; i < MI; i++)
#pragma unroll
    for (int j = 0; j < NJ; j++) acc[i][j] = (f32x4){0.f, 0.f, 0.f, 0.f};

  const u16* Ab = A + (size_t)m0 * K;
  const u16* Bb = Bt + (size_t)n0 * K;

  for (int k0 = k_begin; k0 < k_end; k0 += BK){
    __syncthreads();                    // previous compute done with LDS
#pragma unroll
    for (int r = 0; r < RA; ++r){
      int c = r * 256 + tid;
      int row = c >> 3, kk = (c & 7) << 3;
      gload_lds16(Ab + (size_t)row * K + k0 + kk, &As[(r * 256 + wave * 64) * 8]);
    }
#pragma unroll
    for (int r = 0; r < RB; ++r){
      int c = r * 256 + tid;
      int row = c >> 3, kk = (c & 7) << 3;
      gload_lds16(Bb + (size_t)row * K + k0 + kk, &Bs[(r * 256 + wave * 64) * 8]);
    }
    __syncthreads();                    // staging complete (compiler drains vmcnt)
#pragma unroll
    for (int kh = 0; kh < 2; ++kh){
      bf16x8 af[MI], bfv[NJ];
#pragma unroll
      for (int i = 0; i < MI; ++i)
        af[i] = *reinterpret_cast<const bf16x8*>(&As[(wm + i * 16 + lrow) * BK + kh * 32 + lg * 8]);
#pragma unroll
      for (int j = 0; j < NJ; ++j)
        bfv[j] = *reinterpret_cast<const bf16x8*>(&Bs[(wn + j * 16 + lrow) * BK + kh * 32 + lg * 8]);
#pragma unroll
      for (int i = 0; i < MI; ++i)
#pragma unroll
        for (int j = 0; j < NJ; ++j)
          acc[i][j] = __builtin_amdgcn_mfma_f32_16x16x32_bf16(af[i], bfv[j], acc[i][j], 0, 0, 0);
    }
  }

#pragma unroll
  for (int i = 0; i < MI; ++i){
#pragma unroll
    for (int j = 0; j < NJ; ++j){
      int col = n0 + wn + j * 16 + lrow;
      float bv = (OM != 4 && bias) ? bias[col] : 0.f;
#pragma unroll
      for (int r = 0; r < 4; ++r){
        int row = m0 + wm + i * 16 + lg * 4 + r;
        float x = acc[i][j][r] + bv;
        if (OM == 1){
          if (col < 2048) x = 1.f / (1.f + expf(-x));
          int which = col >> 10, cc = col & 1023, h = cc >> 6, d = cc & 63;
          int b = row >> 10, l = row & 1023;
          outF[(size_t)which * (2048ull * 1024) +
               (((size_t)(b * 16 + h)) * 1024 + l) * 64 + d] = x;
        } else if (OM == 4){
          outF[((size_t)blockIdx.z * M + row) * N + col] = x;
        } else {
          if (ACT == 2) x = 0.5f * x * (1.f + erff(x * 0.70710678118654752f));
          if (OM == 0) outF[(size_t)row * N + col] = x;
          else if (OM == 2){
            size_t idx = (size_t)row * N + col;
            outF[idx] = x + resid[idx];
          } else {
            outB[(size_t)row * N + col] = f2bf(x);
          }
        }
      }
    }
  }
}

// ---------------- attention scalar pipeline (chunked Gram-tile form) ----------------
__global__ __launch_bounds__(256) void chunk_sums(const float* __restrict__ k, const float* __restrict__ q,
                                                  float* __restrict__ ck, float* __restrict__ cq){
  int blk = blockIdx.x;
  int lane = threadIdx.x & 63, wave = threadIdx.x >> 6;
  size_t base = (size_t)blk * 64 * DHD;
  float sk = 0.f, sq = 0.f;
  for (int l = wave * 16; l < wave * 16 + 16; l++){
    sk += k[base + l * 64 + lane];
    sq += q[base + l * 64 + lane];
  }
  __shared__ float rd[2][4][64];
  rd[0][wave][lane] = sk; rd[1][wave][lane] = sq;
  __syncthreads();
  if (wave == 0){
    ck[(size_t)blk * 64 + lane] = rd[0][0][lane] + rd[0][1][lane] + rd[0][2][lane] + rd[0][3][lane];
    cq[(size_t)blk * 64 + lane] = rd[1][0][lane] + rd[1][1][lane] + rd[1][2][lane] + rd[1][3][lane];
  }
}

// sink_in/src_out via G = Q K^T tile; also emits weighted chunk sums cso=sum so*k, cqsi=sum si*q
__global__ __launch_bounds__(256) void sink_tile(
    const float* __restrict__ q, const float* __restrict__ k,
    const float* __restrict__ ck, const float* __restrict__ cq,
    float* __restrict__ sink_in, float* __restrict__ src_out,
    float* __restrict__ cso, float* __restrict__ cqsi)
{
  int blk = blockIdx.x, bh = blk >> 4, c = blk & 15;
  int tid = threadIdx.x, lane = tid & 63, wave = tid >> 6;
  __shared__ float qT[64][65], kT[64][65], G[64][66];
  __shared__ float PK[64], PQ[64];
  __shared__ float rk[64], rq[64], crk[64], crq[64], siv[64], sov[64];
  __shared__ float rd[2][4][64];
  size_t base = ((size_t)bh * LSEQ + c * 64) * DHD;
  const float* qb = q + base; const float* kb = k + base;
  for (int c4 = tid; c4 < 1024; c4 += 256){
    int l = c4 >> 4, d0 = (c4 & 15) * 4;
    float4 qv = *reinterpret_cast<const float4*>(qb + c4 * 4);
    qT[d0+0][l] = qv.x; qT[d0+1][l] = qv.y; qT[d0+2][l] = qv.z; qT[d0+3][l] = qv.w;
    float4 kv = *reinterpret_cast<const float4*>(kb + c4 * 4);
    kT[d0+0][l] = kv.x; kT[d0+1][l] = kv.y; kT[d0+2][l] = kv.z; kT[d0+3][l] = kv.w;
  }
  if (tid < 64){
    float pk = 0.f, pq = 0.f;
    for (int cc = 0; cc < c; cc++){
      pk += ck[((size_t)bh * 16 + cc) * 64 + tid];
      pq += cq[((size_t)bh * 16 + cc) * 64 + tid];
    }
    PK[tid] = pk; PQ[tid] = pq;
  }
  __syncthreads();
  for (int j = wave * 16; j < wave * 16 + 16; j++){
    float s = wred64(kT[lane][j]);  if (lane == 0) rk[j] = s;
    float s2 = wred64(qT[lane][j]); if (lane == 0) rq[j] = s2;
  }
  float sumPK = wred64(PK[lane]);
  float sumPQ = wred64(PQ[lane]);
  {
    int l = lane, g = wave;
    float qrow[64];
#pragma unroll
    for (int d = 0; d < 64; d++) qrow[d] = qT[d][l];
    float p[16] = {};
    for (int d = 0; d < 64; d++){
      float qv = qrow[d];
#pragma unroll
      for (int j4 = 0; j4 < 4; j4++){
        float4 kk = *reinterpret_cast<const float4*>(&kT[d][g * 16 + j4 * 4]);
        p[j4*4+0] += qv * kk.x; p[j4*4+1] += qv * kk.y;
        p[j4*4+2] += qv * kk.z; p[j4*4+3] += qv * kk.w;
      }
    }
#pragma unroll
    for (int jj = 0; jj < 16; jj++) G[l][g * 16 + jj] = p[jj];
  }
  __syncthreads();
  if (wave == 0)      crk[lane] = wscan64(rk[lane], lane);
  else if (wave == 1) crq[lane] = wscan64(rq[lane], lane);
  __syncthreads();
  const float EPS2 = 64.f * EPS * EPS;
  for (int l = wave * 16; l < wave * 16 + 16; l++){
    float t1 = ((lane <= l) ? G[l][lane] : 0.f) + qT[lane][l] * PK[lane];
    float s1 = wred64(t1);
    float t2 = ((lane <= l) ? G[lane][l] : 0.f) + kT[lane][l] * PQ[lane];
    float s2 = wred64(t2);
    if (lane == 0){
      int L = c * 64 + l; float nrm = (float)(L + 1);
      float den1 = s1 + EPS * rq[l] + EPS * (sumPK + crk[l]) + EPS2;
      float den2 = s2 + EPS * rk[l] + EPS * (sumPQ + crq[l]) + EPS2;
      float si_ = nrm / den1, so_ = nrm / den2;
      sink_in[(size_t)bh * LSEQ + L] = si_;
      src_out[(size_t)bh * LSEQ + L] = so_;
      siv[l] = si_; sov[l] = so_;
    }
  }
  __syncthreads();
  float s1 = 0.f, s2 = 0.f;
  for (int l = wave * 16; l < wave * 16 + 16; l++){
    s1 += sov[l] * kT[lane][l];
    s2 += siv[l] * qT[lane][l];
  }
  rd[0][wave][lane] = s1; rd[1][wave][lane] = s2;
  __syncthreads();
  if (wave == 0){
    cso [(size_t)blk * 64 + lane] = rd[0][0][lane] + rd[0][1][lane] + rd[0][2][lane] + rd[0][3][lane];
    cqsi[(size_t)blk * 64 + lane] = rd[1][0][lane] + rd[1][1][lane] + rd[1][2][lane] + rd[1][3][lane];
  }
}

// cons_sink -> sa = sigmoid; cons_src -> clip -> ebuf = exp
__global__ __launch_bounds__(256) void cons_tile(
    const float* __restrict__ q, const float* __restrict__ k,
    const float* __restrict__ cso, const float* __restrict__ cqsi,
    const float* __restrict__ sink_in, const float* __restrict__ src_out,
    float* __restrict__ sa, float* __restrict__ ebuf)
{
  int blk = blockIdx.x, bh = blk >> 4, c = blk & 15;
  int tid = threadIdx.x, lane = tid & 63, wave = tid >> 6;
  __shared__ float qT[64][65], kT[64][65], G[64][66];
  __shared__ float PKso[64], PQsi[64];
  __shared__ float rk[64], rq[64], cwrk[64], cwrq[64], siv[64], sov[64];
  size_t base = ((size_t)bh * LSEQ + c * 64) * DHD;
  const float* qb = q + base; const float* kb = k + base;
  for (int c4 = tid; c4 < 1024; c4 += 256){
    int l = c4 >> 4, d0 = (c4 & 15) * 4;
    float4 qv = *reinterpret_cast<const float4*>(qb + c4 * 4);
    qT[d0+0][l] = qv.x; qT[d0+1][l] = qv.y; qT[d0+2][l] = qv.z; qT[d0+3][l] = qv.w;
    float4 kv = *reinterpret_cast<const float4*>(kb + c4 * 4);
    kT[d0+0][l] = kv.x; kT[d0+1][l] = kv.y; kT[d0+2][l] = kv.z; kT[d0+3][l] = kv.w;
  }
  if (tid < 64){
    float pk = 0.f, pq = 0.f;
    for (int cc = 0; cc < c; cc++){
      pk += cso [((size_t)bh * 16 + cc) * 64 + tid];
      pq += cqsi[((size_t)bh * 16 + cc) * 64 + tid];
    }
    PKso[tid] = pk; PQsi[tid] = pq;
  } else if (tid < 128){
    int l = tid - 64;
    sov[l] = src_out[(size_t)bh * LSEQ + c * 64 + l];
    siv[l] = sink_in[(size_t)bh * LSEQ + c * 64 + l];
  }
  __syncthreads();
  for (int j = wave * 16; j < wave * 16 + 16; j++){
    float s = wred64(kT[lane][j]);  if (lane == 0) rk[j] = s;
    float s2 = wred64(qT[lane][j]); if (lane == 0) rq[j] = s2;
  }
  float sumPKso = wred64(PKso[lane]);
  float sumPQsi = wred64(PQsi[lane]);
  {
    int l = lane, g = wave;
    float qrow[64];
#pragma unroll
    for (int d = 0; d < 64; d++) qrow[d] = qT[d][l];
    float p[16] = {};
    for (int d = 0; d < 64; d++){
      float qv = qrow[d];
#pragma unroll
      for (int j4 = 0; j4 < 4; j4++){
        float4 kk = *reinterpret_cast<const float4*>(&kT[d][g * 16 + j4 * 4]);
        p[j4*4+0] += qv * kk.x; p[j4*4+1] += qv * kk.y;
        p[j4*4+2] += qv * kk.z; p[j4*4+3] += qv * kk.w;
      }
    }
#pragma unroll
    for (int jj = 0; jj < 16; jj++) G[l][g * 16 + jj] = p[jj];
  }
  __syncthreads();
  if (wave == 0)      cwrk[lane] = wscan64(sov[lane] * rk[lane], lane);
  else if (wave == 1) cwrq[lane] = wscan64(siv[lane] * rq[lane], lane);
  __syncthreads();
  const float EPS2 = 64.f * EPS * EPS;
  for (int l = wave * 16; l < wave * 16 + 16; l++){
    float t3 = ((lane <= l) ? sov[lane] * G[l][lane] : 0.f) + qT[lane][l] * PKso[lane];
    float s3 = wred64(t3);
    float t4 = ((lane <= l) ? siv[lane] * G[lane][l] : 0.f) + kT[lane][l] * PQsi[lane];
    float s4 = wred64(t4);
    if (lane == 0){
      int L = c * 64 + l; float nrm = (float)(L + 1);
      float cs = (s3 + EPS * rq[l] + EPS * (sumPKso + cwrk[l]) + EPS2) / nrm;
      sa[(size_t)bh * LSEQ + L] = 1.f / (1.f + expf(-cs));
      float c2 = (s4 + EPS * rk[l] + EPS * (sumPQsi + cwrq[l]) + EPS2) / nrm;
      c2 = fminf(1.f, fmaxf(-1.f, c2));
      ebuf[(size_t)bh * LSEQ + L] = expf(c2);
    }
  }
}

// src_comp = e / cumsum(e) * (l+1)
__global__ __launch_bounds__(64) void srccomp_kernel(const float* __restrict__ ebuf, float* __restrict__ sc){
  int bh = blockIdx.x; int lane = threadIdx.x;
  const float* eb = ebuf + (size_t)bh * LSEQ;
  float loc[16]; float s = 0.f;
#pragma unroll
  for (int i = 0; i < 16; i++){ loc[i] = eb[lane * 16 + i]; s += loc[i]; }
  float run = wscan64(s, lane);
  float acc = run - s;
  float* scb = sc + (size_t)bh * LSEQ;
#pragma unroll
  for (int i = 0; i < 16; i++){
    acc += loc[i];
    scb[lane * 16 + i] = loc[i] / acc * (float)(lane * 16 + i + 1);
  }
}

// qs = q*sink_in/(l+1);  vs = v*src_comp
__global__ __launch_bounds__(256) void scale_kernel(const float* __restrict__ q, const float* __restrict__ v,
                                                    const float* __restrict__ si, const float* __restrict__ sc,
                                                    float* __restrict__ qs, float* __restrict__ vs){
  int i0 = (blockIdx.x * 256 + threadIdx.x) * 8;
  int r = i0 >> 6; int l = r & (LSEQ - 1);
  float qcoef = si[r] / (float)(l + 1);
  float vcoef = sc[r];
#pragma unroll
  for (int t = 0; t < 8; t += 4){
    float4 qv = *reinterpret_cast<const float4*>(q + i0 + t);
    float4 vv = *reinterpret_cast<const float4*>(v + i0 + t);
    *reinterpret_cast<float4*>(qs + i0 + t) = make_float4(qv.x*qcoef, qv.y*qcoef, qv.z*qcoef, qv.w*qcoef);
    *reinterpret_cast<float4*>(vs + i0 + t) = make_float4(vv.x*vcoef, vv.y*vcoef, vv.z*vcoef, vv.w*vcoef);
  }
}

// ---------------- chunked causal linear attention ----------------
__global__ __launch_bounds__(256) void phaseA(const float* __restrict__ k, const float* __restrict__ vs,
                                              float* __restrict__ S){
  int blk = blockIdx.x; int bh = blk >> 4, c = blk & 15;
  __shared__ float ks[64][68], vss[64][68];
  int tid = threadIdx.x;
  size_t base = ((size_t)bh * LSEQ + c * 64) * DHD;
  const float* kb = k + base; const float* vb = vs + base;
  for (int c4 = tid; c4 < 1024; c4 += 256){
    int l = c4 >> 4, d0 = (c4 & 15) * 4;
    *reinterpret_cast<float4*>(&ks[l][d0])  = *reinterpret_cast<const float4*>(kb + c4 * 4);
    *reinterpret_cast<float4*>(&vss[l][d0]) = *reinterpret_cast<const float4*>(vb + c4 * 4);
  }
  __syncthreads();
  int m = tid >> 2, dg = tid & 3;
  float acc[16] = {};
  for (int l = 0; l < 64; l++){
    float vm = vss[l][m];
#pragma unroll
    for (int d4 = 0; d4 < 4; d4++){
      float4 kk = *reinterpret_cast<const float4*>(&ks[l][dg * 16 + d4 * 4]);
      acc[d4*4+0] += vm * kk.x; acc[d4*4+1] += vm * kk.y;
      acc[d4*4+2] += vm * kk.z; acc[d4*4+3] += vm * kk.w;
    }
  }
  float* Sb = S + (size_t)blk * 4096 + m * 64 + dg * 16;
#pragma unroll
  for (int d4 = 0; d4 < 4; d4++)
    *reinterpret_cast<float4*>(Sb + d4 * 4) =
        make_float4(acc[d4*4], acc[d4*4+1], acc[d4*4+2], acc[d4*4+3]);
}

__global__ __launch_bounds__(256) void phaseB(const float* __restrict__ S, float* __restrict__ KVp){
  int bh = blockIdx.x; int tid = threadIdx.x;
  int off = tid * 16;
  float acc[16] = {};
  for (int c = 0; c < 16; c++){
    size_t idx = ((size_t)bh * 16 + c) * 4096 + off;
#pragma unroll
    for (int t = 0; t < 4; t++)
      *reinterpret_cast<float4*>(KVp + idx + t * 4) =
          make_float4(acc[t*4], acc[t*4+1], acc[t*4+2], acc[t*4+3]);
#pragma unroll
    for (int t = 0; t < 4; t++){
      float4 sv = *reinterpret_cast<const float4*>(S + idx + t * 4);
      acc[t*4] += sv.x; acc[t*4+1] += sv.y; acc[t*4+2] += sv.z; acc[t*4+3] += sv.w;
    }
  }
}

__global__ __launch_bounds__(256) void phaseC(const float* __restrict__ qs, const float* __restrict__ k,
                                              const float* __restrict__ vs, const float* __restrict__ KVp,
                                              const float* __restrict__ sa, u16* __restrict__ x){
  int blk = blockIdx.x; int bh = blk >> 4, c = blk & 15;
  int b = bh >> 4, h = bh & 15;
  __shared__ float qsT[64][65];
  __shared__ float kT[64][68];
  __shared__ float vss[64][68];
  __shared__ float kvs[64][68];
  __shared__ float Ps[64][66];
  int tid = threadIdx.x;
  size_t base = ((size_t)bh * LSEQ + c * 64) * DHD;
  const float* qb = qs + base; const float* kb = k + base; const float* vb = vs + base;
  const float* kvb = KVp + (size_t)blk * 4096;
  for (int c4 = tid; c4 < 1024; c4 += 256){
    int l = c4 >> 4, d0 = (c4 & 15) * 4;
    float4 qv = *reinterpret_cast<const float4*>(qb + c4 * 4);
    qsT[d0+0][l] = qv.x; qsT[d0+1][l] = qv.y; qsT[d0+2][l] = qv.z; qsT[d0+3][l] = qv.w;
    float4 kv4 = *reinterpret_cast<const float4*>(kb + c4 * 4);
    kT[d0+0][l] = kv4.x; kT[d0+1][l] = kv4.y; kT[d0+2][l] = kv4.z; kT[d0+3][l] = kv4.w;
    *reinterpret_cast<float4*>(&vss[l][d0]) = *reinterpret_cast<const float4*>(vb + c4 * 4);
    *reinterpret_cast<float4*>(&kvs[l][d0]) = *reinterpret_cast<const float4*>(kvb + c4 * 4);
  }
  __syncthreads();
  int l = tid & 63, g = tid >> 6;
  float qrow[64];
#pragma unroll
  for (int d = 0; d < 64; d++) qrow[d] = qsT[d][l];

  float p[16] = {};
  for (int d = 0; d < 64; d++){
    float qv = qrow[d];
#pragma unroll
    for (int j4 = 0; j4 < 4; j4++){
      float4 kk = *reinterpret_cast<const float4*>(&kT[d][g * 16 + j4 * 4]);
      p[j4*4+0] += qv * kk.x; p[j4*4+1] += qv * kk.y;
      p[j4*4+2] += qv * kk.z; p[j4*4+3] += qv * kk.w;
    }
  }
#pragma unroll
  for (int jj = 0; jj < 16; jj++){
    int j = g * 16 + jj;
    Ps[l][j] = (j <= l) ? p[jj] : 0.f;
  }
  __syncthreads();

  float acc[16];
#pragma unroll
  for (int mm = 0; mm < 16; mm++){
    float a = 0.f;
#pragma unroll
    for (int d4 = 0; d4 < 16; d4++){
      float4 kv4 = *reinterpret_cast<const float4*>(&kvs[g * 16 + mm][d4 * 4]);
      a += qrow[d4*4+0]*kv4.x + qrow[d4*4+1]*kv4.y + qrow[d4*4+2]*kv4.z + qrow[d4*4+3]*kv4.w;
    }
    acc[mm] = a;
  }
  for (int j = 0; j < 64; j++){
    float pv = Ps[l][j];
#pragma unroll
    for (int m4 = 0; m4 < 4; m4++){
      float4 vv = *reinterpret_cast<const float4*>(&vss[j][g * 16 + m4 * 4]);
      acc[m4*4+0] += pv * vv.x; acc[m4*4+1] += pv * vv.y;
      acc[m4*4+2] += pv * vv.z; acc[m4*4+3] += pv * vv.w;
    }
  }
  float sav = sa[(size_t)bh * LSEQ + c * 64 + l];
  u16* xo = x + ((size_t)(b * 1024 + c * 64 + l)) * 1024 + h * 64 + g * 16;
#pragma unroll
  for (int mm = 0; mm < 16; mm++) xo[mm] = f2bf(acc[mm] * sav);
}

// ---------------- layernorm (optionally emits bf16 copy) ----------------
__global__ __launch_bounds__(256) void ln_kernel(const float* __restrict__ xin, const float* __restrict__ g,
                                                 const float* __restrict__ b, float* __restrict__ out,
                                                 u16* __restrict__ outbf){
  int row = blockIdx.x; int tid = threadIdx.x;
  int lane = tid & 63, wave = tid >> 6;
  const float* xr = xin + (size_t)row * 1024;
  float4 v = *reinterpret_cast<const float4*>(xr + tid * 4);
  float s = v.x + v.y + v.z + v.w;
  float s2 = v.x*v.x + v.y*v.y + v.z*v.z + v.w*v.w;
  s = wred64(s); s2 = wred64(s2);
  __shared__ float red[2][4];
  if (lane == 0){ red[0][wave] = s; red[1][wave] = s2; }
  __syncthreads();
  float S = red[0][0] + red[0][1] + red[0][2] + red[0][3];
  float S2 = red[1][0] + red[1][1] + red[1][2] + red[1][3];
  float mean = S * (1.f / 1024.f);
  float var = S2 * (1.f / 1024.f) - mean * mean;
  float inv = rsqrtf(var + 1e-5f);
  float4 gv = *reinterpret_cast<const float4*>(g + tid * 4);
  float4 bv = *reinterpret_cast<const float4*>(b + tid * 4);
  float y0 = (v.x - mean) * inv * gv.x + bv.x;
  float y1 = (v.y - mean) * inv * gv.y + bv.y;
  float y2 = (v.z - mean) * inv * gv.z + bv.z;
  float y3 = (v.w - mean) * inv * gv.w + bv.w;
  *reinterpret_cast<float4*>(out + (size_t)row * 1024 + tid * 4) = make_float4(y0, y1, y2, y3);
  if (outbf){
    ushort4 o; o.x = f2bf(y0); o.y = f2bf(y1); o.z = f2bf(y2); o.w = f2bf(y3);
    *reinterpret_cast<ushort4*>(outbf + (size_t)row * 1024 + tid * 4) = o;
  }
}

// layernorm over (p0 + p1 + bias + resid)  -- fuses the split-K reduce of FFN2
__global__ __launch_bounds__(256) void ln_fused2(
    const float* __restrict__ p0, const float* __restrict__ p1,
    const float* __restrict__ resid, const float* __restrict__ bias,
    const float* __restrict__ g, const float* __restrict__ b,
    float* __restrict__ out){
  int row = blockIdx.x; int tid = threadIdx.x;
  int lane = tid & 63, wave = tid >> 6;
  size_t off = (size_t)row * 1024 + tid * 4;
  float4 a0 = *reinterpret_cast<const float4*>(p0 + off);
  float4 a1 = *reinterpret_cast<const float4*>(p1 + off);
  float4 rr = *reinterpret_cast<const float4*>(resid + off);
  float4 bb = *reinterpret_cast<const float4*>(bias + tid * 4);
  float4 v = make_float4(a0.x + a1.x + rr.x + bb.x, a0.y + a1.y + rr.y + bb.y,
                         a0.z + a1.z + rr.z + bb.z, a0.w + a1.w + rr.w + bb.w);
  float s = v.x + v.y + v.z + v.w;
  float s2 = v.x*v.x + v.y*v.y + v.z*v.z + v.w*v.w;
  s = wred64(s); s2 = wred64(s2);
  __shared__ float red[2][4];
  if (lane == 0){ red[0][wave] = s; red[1][wave] = s2; }
  __syncthreads();
  float S = red[0][0] + red[0][1] + red[0][2] + red[0][3];
  float S2 = red[1][0] + red[1][1] + red[1][2] + red[1][3];
  float mean = S * (1.f / 1024.f);
  float var = S2 * (1.f / 1024.f) - mean * mean;
  float inv = rsqrtf(var + 1e-5f);
  float4 gv = *reinterpret_cast<const float4*>(g + tid * 4);
  float4 bv = *reinterpret_cast<const float4*>(b + tid * 4);
  float y0 = (v.x - mean) * inv * gv.x + bv.x;
  float y1 = (v.y - mean) * inv * gv.y + bv.y;
  float y2 = (v.z - mean) * inv * gv.z + bv.z;
  float y3 = (v.w - mean) * inv * gv.w + bv.w;
  *reinterpret_cast<float4*>(out + off) = make_float4(y0, y1, y2, y3);
}

// ---------------- launch ----------------
extern "C" void kernel_launch(void* const* d_in, const int* in_sizes, int n_in,
                              void* d_out, int out_size, void* d_ws, size_t ws_size,
                              hipStream_t stream){
  (void)in_sizes; (void)n_in; (void)out_size; (void)ws_size;
  const float* inputs = (const float*)d_in[0];
  const float* Wq = (const float*)d_in[2];  const float* bq = (const float*)d_in[3];
  const float* Wk = (const float*)d_in[4];  const float* bk = (const float*)d_in[5];
  const float* Wv = (const float*)d_in[6];  const float* bv = (const float*)d_in[7];
  const float* Wo = (const float*)d_in[8];  const float* bo = (const float*)d_in[9];
  const float* ln1g = (const float*)d_in[10]; const float* ln1b = (const float*)d_in[11];
  const float* W1 = (const float*)d_in[12]; const float* b1 = (const float*)d_in[13];
  const float* W2 = (const float*)d_in[14]; const float* b2 = (const float*)d_in[15];
  const float* ln2g = (const float*)d_in[16]; const float* ln2b = (const float*)d_in[17];
  float* out = (float*)d_out;

  char* wsp = (char*)d_ws; size_t off = 0;
  auto alloc = [&](size_t bytes) -> void* {
    off = (off + 255) & ~(size_t)255;
    void* p = wsp + off; off += bytes; return p;
  };
  const size_t MD = (size_t)2048 * 1024;
  u16* Xbf    = (u16*)alloc(MD * 2);
  u16* WqkvT  = (u16*)alloc((size_t)3 * 1024 * 1024 * 2);
  u16* WoT    = (u16*)alloc((size_t)1024 * 1024 * 2);
  u16* W1T    = (u16*)alloc((size_t)4096 * 1024 * 2);
  u16* W2T    = (u16*)alloc((size_t)4096 * 1024 * 2);
  float* bqkv = (float*)alloc(3072 * 4);
  float* qkvb = (float*)alloc(3 * MD * 4);
  float* qb = qkvb; float* kb = qkvb + MD; float* vb = qkvb + 2 * MD;
  float* c1 = (float*)alloc(MD * 4);            // qs
  float* c2 = (float*)alloc(MD * 4);            // vs
  float* ckb  = (float*)alloc((size_t)512 * 64 * 4);
  float* cqb  = (float*)alloc((size_t)512 * 64 * 4);
  float* csob = (float*)alloc((size_t)512 * 64 * 4);
  float* cqsib= (float*)alloc((size_t)512 * 64 * 4);
  float* sink_in = (float*)alloc(NBH * LSEQ * 4);
  float* src_out = (float*)alloc(NBH * LSEQ * 4);
  float* sabuf   = (float*)alloc(NBH * LSEQ * 4);
  float* ebuf    = (float*)alloc(NBH * LSEQ * 4);
  float* scbuf   = (float*)alloc(NBH * LSEQ * 4);
  float* Sbuf = (float*)alloc((size_t)NBH * 16 * 4096 * 4);   // 8 MB
  float* KVp  = (float*)alloc((size_t)NBH * 16 * 4096 * 4);   // 8 MB (contiguous after Sbuf)
  u16* xatt   = (u16*)alloc(MD * 2);
  u16* g1     = (u16*)alloc((size_t)2048 * 4096 * 2);
  // reuse: s1 <- qb, hbuf <- vb, hbf <- Sbuf (bf16 LN1 out),
  //        FFN2 split-K partials <- Sbuf..KVp (16 MB, alive after FFN1 consumed hbf)
  float* s1 = qb;
  float* hbuf = vb;
  u16* hbf = (u16*)Sbuf;
  float* part = (float*)Sbuf;     // [2][2048][1024] f32

  // converts + weight prep
  f2bf_kernel<<<2048, 256, 0, stream>>>(inputs, Xbf, (int)(MD / 4));
  transpose4_f2bf<<<dim3(32, 32, 4), 256, 0, stream>>>(Wq, Wk, Wv, Wo, WqkvT, WoT);
  transpose_f2bf<<<dim3(128, 32), 256, 0, stream>>>(W1, W1T, 1024, 4096);
  transpose_f2bf<<<dim3(32, 128), 256, 0, stream>>>(W2, W2T, 4096, 1024);
  bias_gather<<<12, 256, 0, stream>>>(bq, bk, bv, bqkv);

  // fused QKV projection: BM=64,BN=128, grid 32x24 = 768 blocks (3/CU)
  gemm_mfma<64, 128, 0, 1><<<dim3(32, 24), 256, 0, stream>>>(
      Xbf, WqkvT, bqkv, nullptr, qkvb, nullptr, 2048, 3072, 1024);

  // attention scalars (chunked Gram-tile pipeline)
  chunk_sums<<<512, 256, 0, stream>>>(kb, qb, ckb, cqb);
  sink_tile<<<512, 256, 0, stream>>>(qb, kb, ckb, cqb, sink_in, src_out, csob, cqsib);
  cons_tile<<<512, 256, 0, stream>>>(qb, kb, csob, cqsib, sink_in, src_out, sabuf, ebuf);
  srccomp_kernel<<<32, 64, 0, stream>>>(ebuf, scbuf);
  scale_kernel<<<1024, 256, 0, stream>>>(qb, vb, sink_in, scbuf, c1, c2);

  // chunked causal linear attention
  phaseA<<<512, 256, 0, stream>>>(kb, c2, Sbuf);
  phaseB<<<32, 256, 0, stream>>>(Sbuf, KVp);
  phaseC<<<512, 256, 0, stream>>>(c1, kb, c2, KVp, sabuf, xatt);

  // output projection + residual: BM=64,BN=64, grid 32x16 = 512 blocks
  gemm_mfma<64, 64, 0, 2><<<dim3(32, 16), 256, 0, stream>>>(
      xatt, WoT, bo, inputs, s1, nullptr, 2048, 1024, 1024);
  ln_kernel<<<2048, 256, 0, stream>>>(s1, ln1g, ln1b, hbuf, hbf);

  // FFN1: BM=64,BN=128, grid 32x32 = 1024 blocks (4/CU)
  gemm_mfma<64, 128, 2, 3><<<dim3(32, 32), 256, 0, stream>>>(
      hbf, W1T, b1, nullptr, nullptr, g1, 2048, 4096, 1024);
  // FFN2: BM=64,BN=64, split-K=2, grid 32x16x2 = 1024 blocks (4/CU), raw partials
  gemm_mfma<64, 64, 0, 4><<<dim3(32, 16, 2), 256, 0, stream>>>(
      g1, W2T, nullptr, nullptr, part, nullptr, 2048, 1024, 4096);
  // LN2 fused with split-K reduce + bias + residual
  ln_fused2<<<2048, 256, 0, stream>>>(part, part + MD, hbuf, b2, ln2g, ln2b, out);
}